// Round 9
// baseline (240.956 us; speedup 1.0000x reference)
//
#include <hip/hip_runtime.h>
#include <stdint.h>
#include <math.h>

#define NB 64      // batch
#define BT 512     // time steps
#define NH 768     // hidden
#define NL 9       // labels
#define PBT 528    // padded time rows in crf LDS

__device__ __forceinline__ float rlane(float v, int i) {
    return __int_as_float(__builtin_amdgcn_readlane(__float_as_int(v), i));
}

// DPP-based cross-lane add: v += dpp_move(v); runs on VALU, NOT the DS pipe.
template<int CTRL, int RM>
__device__ __forceinline__ float dppadd(float v) {
    const int t = __builtin_amdgcn_update_dpp(0, __float_as_int(v), CTRL, RM, 0xf, true);
    return v + __int_as_float(t);
}

// full 64-lane sum -> uniform scalar (read from lane 63)
__device__ __forceinline__ float wave_sum_dpp(float v) {
    v = dppadd<0x111, 0xf>(v);   // row_shr:1
    v = dppadd<0x112, 0xf>(v);   // row_shr:2
    v = dppadd<0x114, 0xf>(v);   // row_shr:4
    v = dppadd<0x118, 0xf>(v);   // row_shr:8  -> lane 15 of each row16 = row sum
    v = dppadd<0x142, 0xa>(v);   // row_bcast:15 into rows 1,3
    v = dppadd<0x143, 0xc>(v);   // row_bcast:31 into rows 2,3 -> lane 63 = total
    return rlane(v, 63);
}

// ---------------------------------------------------------------------------
// Kernel 1: logits = x @ W + b.  Wave-per-row.  k-chunk 0 of W in registers
// (36 VGPRs), chunks 1-2 read from LDS per row (18 conflict-free ds_read_b128).
// VGPR capped for 4 waves/SIMD (2x TLP vs the 108-reg variant that sat at
// 2 waves/SIMD with 90% stall).  Coalesced float4 x loads; 2-deep row
// pipeline; DPP reduce.  Grid 2048 blocks, 4 rows/wave.
// ---------------------------------------------------------------------------
__global__ __launch_bounds__(256, 4) void gemm_kernel(
    const float* __restrict__ x, const float* __restrict__ W,
    const float* __restrict__ bias, float* __restrict__ logits)
{
    __shared__ float wT[NL][NH];   // 27.6 KB: W transposed [l][h]

    const int tid  = threadIdx.x;
    const int lane = tid & 63;

    // stage W transposed into LDS (coalesced global reads, one-time)
    for (int i = tid; i < NH * NL; i += 256) {
        const int h = i / NL, l = i - h * NL;
        wT[l][h] = W[i];
    }
    __syncthreads();

    // register cache for k-chunk 0 only (36 VGPRs)
    float w0r[NL][4];
#pragma unroll
    for (int l = 0; l < NL; ++l) {
        const float4 t4 = *(const float4*)&wT[l][lane * 4];
        w0r[l][0] = t4.x; w0r[l][1] = t4.y; w0r[l][2] = t4.z; w0r[l][3] = t4.w;
    }
    const float bj = bias[lane < NL ? lane : 0];

    const int gwave = (int)((blockIdx.x * blockDim.x + tid) >> 6);
    const int nw    = (int)((gridDim.x * blockDim.x) >> 6);
    const int nrows = NB * BT;
    int row = gwave;
    if (row >= nrows) return;

    const float4* xr = (const float4*)(x + (size_t)row * NH);
    float4 a0 = xr[lane], a1 = xr[64 + lane], a2 = xr[128 + lane];

    while (true) {
        const int nrow = row + nw;
        float4 b0, b1, b2;
        if (nrow < nrows) {   // prefetch next row while computing this one
            const float4* xn = (const float4*)(x + (size_t)nrow * NH);
            b0 = xn[lane]; b1 = xn[64 + lane]; b2 = xn[128 + lane];
        }

        float sum[NL];
#pragma unroll
        for (int l = 0; l < NL; ++l) {
            const float4 w1 = *(const float4*)&wT[l][256 + lane * 4];
            const float4 w2 = *(const float4*)&wT[l][512 + lane * 4];
            float s = a0.x * w0r[l][0];
            s = fmaf(a0.y, w0r[l][1], s);
            s = fmaf(a0.z, w0r[l][2], s);
            s = fmaf(a0.w, w0r[l][3], s);
            s = fmaf(a1.x, w1.x, s);
            s = fmaf(a1.y, w1.y, s);
            s = fmaf(a1.z, w1.z, s);
            s = fmaf(a1.w, w1.w, s);
            s = fmaf(a2.x, w2.x, s);
            s = fmaf(a2.y, w2.y, s);
            s = fmaf(a2.z, w2.z, s);
            s = fmaf(a2.w, w2.w, s);
            sum[l] = wave_sum_dpp(s);
        }
        // lane j (<9) stores sum[j]: static-index select chain
        float outv = sum[0];
#pragma unroll
        for (int l = 1; l < NL; ++l) outv = (lane == l) ? sum[l] : outv;
        if (lane < NL) logits[(size_t)row * NL + lane] = outv + bj;

        row = nrow;
        if (row >= nrows) break;
        a0 = b0; a1 = b1; a2 = b2;
    }
}

// ---------------------------------------------------------------------------
// Kernel 2: per-batch CRF. Block = 256 (4 waves).
//   scan phase unchanged (validated).  Post phase:
//   - bp recompute + nibble-pack fused (per-thread rows, one barrier saved)
//   - backtrack: rows preloaded into wave-0 VGPRs; lane 0 runs the serial
//     chain via v_readlane (ignores EXEC, SGPR lane index ok) + 64-bit
//     extract; tags stored via off-chain ds_write_b8.  ~8 cyc/step vs ~120
//     for the old one-deep LDS-chase.
// ---------------------------------------------------------------------------
__global__ __launch_bounds__(256) void crf_kernel(
    const float* __restrict__ logits, const float* __restrict__ trans,
    const int* __restrict__ label, const int* __restrict__ seqlen,
    float* __restrict__ vit_out, float* __restrict__ stats)
{
    __shared__ __align__(16) float lg_lds[PBT * NL];   // padded, zeros past BT
    __shared__ float    val_lds[BT * NL];              // viterbi alpha vectors
    __shared__ float    trans_lds[NL * NL];
    __shared__ uint64_t packed_lds[BT - 1];
    __shared__ uint8_t  vit_lds[BT];
    __shared__ float    xw[4][4];

    const int b    = blockIdx.x;
    const int tid  = threadIdx.x;
    const int lane = tid & 63;
    const int wv   = tid >> 6;
    const int sl   = seqlen[b];
    const float* lg  = logits + (size_t)b * BT * NL;
    const int*   lab = label + (size_t)b * BT;

    // stage logits (float4) + zero padding + transitions
    {
        const float4* src = (const float4*)lg;
        float4* dst = (float4*)lg_lds;
        for (int idx = tid; idx < BT * NL / 4; idx += 256) dst[idx] = src[idx];
        for (int idx = BT * NL + tid; idx < PBT * NL; idx += 256) lg_lds[idx] = 0.f;
        if (tid < NL * NL) trans_lds[tid] = trans[tid];
    }
    __syncthreads();

    if (wv == 0) {
        // ---- logZ scan, scaled-exp domain ----
        const int j = lane < NL ? lane : 0;
        float E[NL];
#pragma unroll
        for (int i = 0; i < NL; ++i) E[i] = __expf(trans_lds[i * NL + j]) * 0.125f;
        float A = __expf(lg_lds[j]);
        int lc = 0;
        for (int tb = 1; tb < BT + 8; tb += 8) {
            float P[8];
#pragma unroll
            for (int s = 0; s < 8; ++s) P[s] = __expf(lg_lds[(tb + s) * NL + j]);
#pragma unroll
            for (int s = 0; s < 8; ++s) {
                const int t = tb + s;
                const float r0 = rlane(A, 0), r1 = rlane(A, 1), r2 = rlane(A, 2),
                            r3 = rlane(A, 3), r4 = rlane(A, 4), r5 = rlane(A, 5),
                            r6 = rlane(A, 6), r7 = rlane(A, 7), r8 = rlane(A, 8);
                float p0 = r0 * E[0]; p0 = fmaf(r1, E[1], p0); p0 = fmaf(r2, E[2], p0);
                float p1 = r3 * E[3]; p1 = fmaf(r4, E[4], p1); p1 = fmaf(r5, E[5], p1);
                float p2 = r6 * E[6]; p2 = fmaf(r7, E[7], p2); p2 = fmaf(r8, E[8], p2);
                const float An = ((p0 + p1) + p2) * P[s];
                A = (t < sl) ? An : A;
            }
            // exact pow2 renorm: m is positive & normal here.
            const float m = fmaxf(fmaxf(
                fmaxf(fmaxf(rlane(A, 0), rlane(A, 1)), fmaxf(rlane(A, 2), rlane(A, 3))),
                fmaxf(fmaxf(rlane(A, 4), rlane(A, 5)), fmaxf(rlane(A, 6), rlane(A, 7)))),
                rlane(A, 8));
            const int ex = (int)((__float_as_uint(m) >> 23) & 0xFFu) - 126; // frexp exp
            const float sc = __uint_as_float((uint32_t)(127 - ex) << 23);   // 2^-ex
            A *= sc;
            lc += ex;
        }
        const float sum = ((rlane(A, 0) + rlane(A, 1)) + (rlane(A, 2) + rlane(A, 3))) +
                          ((rlane(A, 4) + rlane(A, 5)) + (rlane(A, 6) + rlane(A, 7))) +
                          rlane(A, 8);
        const float logZ = logf(sum) +
            ((float)lc + 3.0f * (float)(sl - 1)) * 0.6931471805599453f;
        if (lane == 0) stats[b * 8 + 1] = logZ;
    } else if (wv == 1) {
        // ---- viterbi value scan; alpha vectors to LDS, argmax deferred ----
        const int j = lane < NL ? lane : 0;
        float tc[NL];
#pragma unroll
        for (int i = 0; i < NL; ++i) tc[i] = trans_lds[i * NL + j];
        float v = lg_lds[j];
        if (lane < NL) val_lds[j] = v;
        for (int tb = 1; tb < BT + 8; tb += 8) {
            float lv[8];
#pragma unroll
            for (int s = 0; s < 8; ++s) lv[s] = lg_lds[(tb + s) * NL + j];
#pragma unroll
            for (int s = 0; s < 8; ++s) {
                const int t = tb + s;
                const float r0 = rlane(v, 0), r1 = rlane(v, 1), r2 = rlane(v, 2),
                            r3 = rlane(v, 3), r4 = rlane(v, 4), r5 = rlane(v, 5),
                            r6 = rlane(v, 6), r7 = rlane(v, 7), r8 = rlane(v, 8);
                const float c0 = r0 + tc[0], c1 = r1 + tc[1], c2 = r2 + tc[2],
                            c3 = r3 + tc[3], c4 = r4 + tc[4], c5 = r5 + tc[5],
                            c6 = r6 + tc[6], c7 = r7 + tc[7], c8 = r8 + tc[8];
                const float m = fmaxf(fmaxf(fmaxf(fmaxf(c0, c1), c2),
                                            fmaxf(fmaxf(c3, c4), c5)),
                                      fmaxf(fmaxf(c6, c7), c8));
                const float nv = m + lv[s];
                v = (t < sl) ? nv : v;
                if (lane < NL && t < BT) val_lds[t * NL + lane] = v;
            }
        }
        // last tag = first-argmax(alphaT)
        const float r0 = rlane(v, 0), r1 = rlane(v, 1), r2 = rlane(v, 2),
                    r3 = rlane(v, 3), r4 = rlane(v, 4), r5 = rlane(v, 5),
                    r6 = rlane(v, 6), r7 = rlane(v, 7), r8 = rlane(v, 8);
        const float m = fmaxf(fmaxf(fmaxf(fmaxf(r0, r1), r2),
                                    fmaxf(fmaxf(r3, r4), r5)),
                              fmaxf(fmaxf(r6, r7), r8));
        const int last = (r0 == m) ? 0 : (r1 == m) ? 1 : (r2 == m) ? 2 :
                         (r3 == m) ? 3 : (r4 == m) ? 4 : (r5 == m) ? 5 :
                         (r6 == m) ? 6 : (r7 == m) ? 7 : 8;
        if (lane == 0) vit_lds[BT - 1] = (uint8_t)last;
    } else if (wv == 2) {
        // ---- gold-path score ----
        float s = 0.f;
        for (int t = lane; t < BT; t += 64) {
            const int lb = lab[t];
            if (t < sl) {
                s += lg_lds[t * NL + lb];
                if (t >= 1) s += trans_lds[lab[t - 1] * NL + lb];
            }
        }
#pragma unroll
        for (int off = 32; off >= 1; off >>= 1) s += __shfl_xor(s, off, 64);
        if (lane == 0) stats[b * 8 + 0] = s;
    }
    __syncthreads();

    // ---- bp recompute + nibble-pack fused (bit-exact first-max) ----
    for (int r = tid; r < BT - 1; r += 256) {
        const int t = r + 1;
        uint64_t p;
        if (t >= sl) {
            p = 0x876543210ULL;          // identity map: nibble j = j
        } else {
            float av[NL];
#pragma unroll
            for (int i = 0; i < NL; ++i) av[i] = val_lds[r * NL + i];
            p = 0;
#pragma unroll
            for (int jj = 0; jj < NL; ++jj) {
                float best = av[0] + trans_lds[jj];
                int bi = 0;
#pragma unroll
                for (int i = 1; i < NL; ++i) {
                    const float c = av[i] + trans_lds[i * NL + jj];
                    if (c > best) { best = c; bi = i; }
                }
                p |= (uint64_t)bi << (4 * jj);
            }
        }
        packed_lds[r] = p;
    }
    __syncthreads();

    // ---- backtrack: rows in wave-0 VGPRs; lane 0 runs the readlane chain ----
    if (wv == 0) {
        uint32_t rlo[8], rhi[8];
#pragma unroll
        for (int c = 0; c < 8; ++c) {
            const int t = c * 64 + lane;
            const uint64_t rv = (t < BT - 1) ? packed_lds[t] : 0x876543210ULL;
            rlo[c] = (uint32_t)(rv & 0xffffffffULL);
            rhi[c] = (uint32_t)(rv >> 32);
        }
        if (lane == 0) {
            int tag = vit_lds[BT - 1];
#pragma unroll
            for (int c = 7; c >= 0; --c) {
                const int istart = (c == 7) ? 62 : 63;   // t=511 has no bp row
                for (int i = istart; i >= 0; --i) {      // uniform (SGPR) lane idx
                    const uint32_t lo = (uint32_t)__builtin_amdgcn_readlane((int)rlo[c], i);
                    const uint32_t hi = (uint32_t)__builtin_amdgcn_readlane((int)rhi[c], i);
                    const uint64_t rowv = ((uint64_t)hi << 32) | lo;
                    tag = (int)((rowv >> (4 * tag)) & 15ULL);
                    vit_lds[c * 64 + i] = (uint8_t)tag;  // off-chain ds_write_b8
                }
            }
        }
    }
    __syncthreads();

    // ---- stats + vit output ----
    float accv = 0.f, tpv = 0.f, tnv = 0.f, fpv = 0.f;
    for (int t = tid; t < BT; t += 256) {
        const int tg = vit_lds[t];
        const int lb = lab[t];
        const bool msk = t < sl;
        vit_out[(size_t)b * BT + t] = (float)tg;
        if (msk && tg == lb) accv += 1.f;
        if (lb > 0 && tg == lb) tpv += 1.f;
        if (lb > 0 && tg != lb) tnv += 1.f;
        if (msk && lb == 0 && tg > 0) fpv += 1.f;
    }
#pragma unroll
    for (int off = 32; off >= 1; off >>= 1) {
        accv += __shfl_xor(accv, off, 64);
        tpv  += __shfl_xor(tpv,  off, 64);
        tnv  += __shfl_xor(tnv,  off, 64);
        fpv  += __shfl_xor(fpv,  off, 64);
    }
    if (lane == 0) { xw[0][wv] = accv; xw[1][wv] = tpv; xw[2][wv] = tnv; xw[3][wv] = fpv; }
    __syncthreads();
    if (tid == 0) {
        stats[b * 8 + 2] = xw[0][0] + xw[0][1] + xw[0][2] + xw[0][3];
        stats[b * 8 + 3] = xw[1][0] + xw[1][1] + xw[1][2] + xw[1][3];
        stats[b * 8 + 4] = xw[2][0] + xw[2][1] + xw[2][2] + xw[2][3];
        stats[b * 8 + 5] = xw[3][0] + xw[3][1] + xw[3][2] + xw[3][3];
    }
}

// ---------------------------------------------------------------------------
// Kernel 3: reduce the 64 per-batch partials -> tp, tn, fp, loss, accuracy
// ---------------------------------------------------------------------------
__global__ __launch_bounds__(64) void finalize_kernel(
    const float* __restrict__ stats, const int* __restrict__ seqlen,
    float* __restrict__ out)
{
    const int lane = threadIdx.x;  // one lane per batch
    float score = stats[lane * 8 + 0];
    float logZ  = stats[lane * 8 + 1];
    float accv  = stats[lane * 8 + 2];
    float tpv   = stats[lane * 8 + 3];
    float tnv   = stats[lane * 8 + 4];
    float fpv   = stats[lane * 8 + 5];
    float nll   = logZ - score;
    float slf   = (float)seqlen[lane];
#pragma unroll
    for (int off = 32; off >= 1; off >>= 1) {
        nll  += __shfl_xor(nll,  off, 64);
        accv += __shfl_xor(accv, off, 64);
        tpv  += __shfl_xor(tpv,  off, 64);
        tnv  += __shfl_xor(tnv,  off, 64);
        fpv  += __shfl_xor(fpv,  off, 64);
        slf  += __shfl_xor(slf,  off, 64);
    }
    if (lane == 0) {
        out[NB * BT + 0] = tpv;
        out[NB * BT + 1] = tnv;
        out[NB * BT + 2] = fpv;
        out[NB * BT + 3] = nll / (float)NB;
        out[NB * BT + 4] = accv / slf;
    }
}

extern "C" void kernel_launch(void* const* d_in, const int* in_sizes, int n_in,
                              void* d_out, int out_size, void* d_ws, size_t ws_size,
                              hipStream_t stream)
{
    const float* x      = (const float*)d_in[0];
    const float* W      = (const float*)d_in[1];
    const float* bias   = (const float*)d_in[2];
    const float* trans  = (const float*)d_in[3];
    const int*   label  = (const int*)d_in[4];
    const int*   seqlen = (const int*)d_in[5];
    // d_in[6] = mask: recomputed from seqlen, unused

    float* out    = (float*)d_out;
    float* logits = (float*)d_ws;                  // 64*512*9 floats
    float* stats  = logits + (size_t)NB * BT * NL; // 64*8 floats

    gemm_kernel<<<2048, 256, 0, stream>>>(x, W, bias, logits);
    crf_kernel<<<NB, 256, 0, stream>>>(logits, trans, label, seqlen, out, stats);
    finalize_kernel<<<1, 64, 0, stream>>>(stats, seqlen, out);
}